// Round 1
// baseline (93.488 us; speedup 1.0000x reference)
//
#include <hip/hip_runtime.h>
#include <hip/hip_bf16.h>

#define B_N 8
#define S_N 4096
#define D_N 64
#define BQ 64
#define BK 64
#define NQT (S_N / BQ)  // 64

typedef __attribute__((ext_vector_type(8))) short bf16x8;
typedef __attribute__((ext_vector_type(4))) float f32x4;

__device__ __forceinline__ float fast_exp2(float x) {
#if __has_builtin(__builtin_amdgcn_exp2f)
  return __builtin_amdgcn_exp2f(x);
#else
  return exp2f(x);
#endif
}

__device__ __forceinline__ unsigned f2bf_u(float x) {
  __hip_bfloat16 h = __float2bfloat16(x);
  return (unsigned)__builtin_bit_cast(unsigned short, h);
}
__device__ __forceinline__ unsigned pack2(float a, float b) {
  return f2bf_u(a) | (f2bf_u(b) << 16);
}
// XOR swizzle within a 128B-row LDS tile; keeps 16B accesses conflict-light
__device__ __forceinline__ int swzoff(int row, int colb) {
  return row * 128 + (colb ^ ((((row & 7) ^ ((row >> 3) & 7))) << 4));
}

#define KB_OFF 0       // K bf16 [2][64][64]   (swizzled rows)
#define VB_OFF 16384   // V^T bf16 [2][64 d][64 k] (swizzled rows)
#define PB_OFF 32768   // P bf16 [4 waves][16 q][64 k] (swizzled rows)

__global__ void __launch_bounds__(256)
lens_kernel(const unsigned* __restrict__ mask, int* __restrict__ lens) {
  int b = blockIdx.x, tid = threadIdx.x;
  unsigned first = mask[0];  // mask[0][0] is always valid (lens >= S/2)
  int cnt = 0;
  if (first == 0x01010101u) {          // bool / int8 layout
    const unsigned char* m = ((const unsigned char*)mask) + (size_t)b * S_N;
    for (int i = tid; i < S_N; i += 256) cnt += (m[i] != 0);
  } else if (first == 0x3F800000u) {   // float layout
    const float* m = ((const float*)mask) + (size_t)b * S_N;
    for (int i = tid; i < S_N; i += 256) cnt += (m[i] != 0.0f);
  } else {                             // int32 layout
    const int* m = ((const int*)mask) + (size_t)b * S_N;
    for (int i = tid; i < S_N; i += 256) cnt += (m[i] != 0);
  }
#pragma unroll
  for (int off = 32; off > 0; off >>= 1) cnt += __shfl_down(cnt, off);
  __shared__ int acc[4];
  if ((tid & 63) == 0) acc[tid >> 6] = cnt;
  __syncthreads();
  if (tid == 0) lens[b] = acc[0] + acc[1] + acc[2] + acc[3];
}

__device__ __forceinline__ void stage_load(const float* __restrict__ Kg,
                                           const float* __restrict__ Vg,
                                           int b, int kv0, int tid,
                                           f32x4 kf[2][2], f32x4 vf[2][2]) {
#pragma unroll
  for (int c = 0; c < 2; ++c) {
    int chunk = c * 256 + tid;
    int kr = chunk >> 3;
    int d0 = (chunk & 7) * 8;
    size_t base = ((size_t)(b * S_N) + kv0 + kr) * D_N + d0;
    kf[c][0] = *(const f32x4*)(Kg + base);
    kf[c][1] = *(const f32x4*)(Kg + base + 4);
    vf[c][0] = *(const f32x4*)(Vg + base);
    vf[c][1] = *(const f32x4*)(Vg + base + 4);
  }
}

__device__ __forceinline__ void stage_write(char* sm, int buf, int tid,
                                            const f32x4 kf[2][2],
                                            const f32x4 vf[2][2]) {
#pragma unroll
  for (int c = 0; c < 2; ++c) {
    int chunk = c * 256 + tid;
    int kr = chunk >> 3;
    int d0 = (chunk & 7) * 8;
    union { bf16x8 v; unsigned u[4]; } pk;
    pk.u[0] = pack2(kf[c][0][0], kf[c][0][1]);
    pk.u[1] = pack2(kf[c][0][2], kf[c][0][3]);
    pk.u[2] = pack2(kf[c][1][0], kf[c][1][1]);
    pk.u[3] = pack2(kf[c][1][2], kf[c][1][3]);
    *(bf16x8*)(sm + KB_OFF + buf * 8192 + swzoff(kr, d0 * 2)) = pk.v;
    // V transposed: Vt[d][k]
#pragma unroll
    for (int e = 0; e < 8; ++e) {
      float v = vf[c][e >> 2][e & 3];
      *(unsigned short*)(sm + VB_OFF + buf * 8192 + swzoff(d0 + e, kr * 2)) =
          (unsigned short)f2bf_u(v);
    }
  }
}

__global__ void __launch_bounds__(256)
attn_kernel(const float* __restrict__ Qg, const float* __restrict__ Kg,
            const float* __restrict__ Vg, const int* __restrict__ lens,
            float* __restrict__ Og) {
  __shared__ char sm[40960];
  const int tid = threadIdx.x;
  const int bid = blockIdx.x;
  const int b = bid & 7;                 // batch -> XCD pinning
  const int qt = (NQT - 1) - (bid >> 3); // heavy q-tiles first
  const int q0 = qt * BQ;
  const int len = lens[b];
  int nt = (len + BK - 1) >> 6;
  if (qt + 1 < nt) nt = qt + 1;          // min(causal, padding)

  const int lane = tid & 63;
  const int w = tid >> 6;
  const int q15 = lane & 15;
  const int hi2 = lane >> 4;             // 0..3
  const int qg = q0 + w * 16 + q15;      // softmax-row owned by this lane

  constexpr float CS = 0.125f * 1.4426950408889634f;  // scale * log2(e)

  // Q fragments (B-operand of swapped QK^T), scale folded in
  bf16x8 qf[2];
#pragma unroll
  for (int dc2 = 0; dc2 < 2; ++dc2) {
    const float* src = Qg + ((size_t)(b * S_N) + qg) * D_N + dc2 * 32 + hi2 * 8;
    f32x4 a = *(const f32x4*)src;
    f32x4 c4 = *(const f32x4*)(src + 4);
    union { bf16x8 v; unsigned u[4]; } pk;
    pk.u[0] = pack2(a[0] * CS, a[1] * CS);
    pk.u[1] = pack2(a[2] * CS, a[3] * CS);
    pk.u[2] = pack2(c4[0] * CS, c4[1] * CS);
    pk.u[3] = pack2(c4[2] * CS, c4[3] * CS);
    qf[dc2] = pk.v;
  }

  f32x4 o[4];
#pragma unroll
  for (int dt = 0; dt < 4; ++dt) o[dt] = (f32x4){0.f, 0.f, 0.f, 0.f};
  float m = -30000.0f, l = 0.0f;

  f32x4 kf[2][2], vf[2][2];
  stage_load(Kg, Vg, b, 0, tid, kf, vf);
  stage_write(sm, 0, tid, kf, vf);
  __syncthreads();

  for (int t = 0; t < nt; ++t) {
    const int buf = t & 1;
    const bool more = (t + 1) < nt;
    if (more) stage_load(Kg, Vg, b, (t + 1) * BK, tid, kf, vf);  // overlap HBM

    // ---- S^T = K · Q^T : lane holds S[qg][k], k = ks*16 + hi2*4 + r ----
    f32x4 st[4];
#pragma unroll
    for (int ks = 0; ks < 4; ++ks) st[ks] = (f32x4){0.f, 0.f, 0.f, 0.f};
#pragma unroll
    for (int dc2 = 0; dc2 < 2; ++dc2) {
#pragma unroll
      for (int ks = 0; ks < 4; ++ks) {
        bf16x8 af = *(const bf16x8*)(sm + KB_OFF + buf * 8192 +
                                     swzoff(ks * 16 + q15, dc2 * 64 + hi2 * 16));
        st[ks] = __builtin_amdgcn_mfma_f32_16x16x32_bf16(af, qf[dc2], st[ks], 0, 0, 0);
      }
    }

    const int kv0 = t * BK;
    if (t == nt - 1) {  // only boundary tile needs causal+padding mask
#pragma unroll
      for (int ks = 0; ks < 4; ++ks)
#pragma unroll
        for (int r = 0; r < 4; ++r) {
          int kg = kv0 + ks * 16 + hi2 * 4 + r;
          if (kg > qg || kg >= len) st[ks][r] = -30000.0f;
        }
    }

    // ---- online softmax (base-2) ----
    float rmax = st[0][0];
#pragma unroll
    for (int ks = 0; ks < 4; ++ks)
#pragma unroll
      for (int r = 0; r < 4; ++r) rmax = fmaxf(rmax, st[ks][r]);
    rmax = fmaxf(rmax, __shfl_xor(rmax, 16));
    rmax = fmaxf(rmax, __shfl_xor(rmax, 32));
    float mnew = fmaxf(m, rmax);
    float alpha = fast_exp2(m - mnew);
    m = mnew;
    float ps = 0.0f;
#pragma unroll
    for (int ks = 0; ks < 4; ++ks)
#pragma unroll
      for (int r = 0; r < 4; ++r) {
        float p = fast_exp2(st[ks][r] - m);
        st[ks][r] = p;
        ps += p;
      }
    ps += __shfl_xor(ps, 16);
    ps += __shfl_xor(ps, 32);
    l = l * alpha + ps;

    // rescale O (alpha for row q = hi2*4 + r lives at lane hi2*4+r)
    float ar[4];
#pragma unroll
    for (int r = 0; r < 4; ++r) ar[r] = __shfl(alpha, hi2 * 4 + r);
#pragma unroll
    for (int dt = 0; dt < 4; ++dt)
#pragma unroll
      for (int r = 0; r < 4; ++r) o[dt][r] *= ar[r];

    // ---- relay P through per-wave LDS strip (same-wave, no barrier) ----
#pragma unroll
    for (int ks = 0; ks < 4; ++ks) {
      uint2 pw = make_uint2(pack2(st[ks][0], st[ks][1]),
                            pack2(st[ks][2], st[ks][3]));
      *(uint2*)(sm + PB_OFF + w * 2048 + swzoff(q15, ks * 32 + hi2 * 8)) = pw;
    }

    // ---- O += P · V ----
#pragma unroll
    for (int kc2 = 0; kc2 < 2; ++kc2) {
      bf16x8 pf = *(const bf16x8*)(sm + PB_OFF + w * 2048 +
                                   swzoff(q15, kc2 * 64 + hi2 * 16));
#pragma unroll
      for (int dt = 0; dt < 4; ++dt) {
        bf16x8 vfr = *(const bf16x8*)(sm + VB_OFF + buf * 8192 +
                                      swzoff(dt * 16 + q15, kc2 * 64 + hi2 * 16));
        o[dt] = __builtin_amdgcn_mfma_f32_16x16x32_bf16(pf, vfr, o[dt], 0, 0, 0);
      }
    }

    if (more) stage_write(sm, buf ^ 1, tid, kf, vf);
    __syncthreads();
  }

  // ---- epilogue: O /= l, store fp32 ----
  float linv[4];
#pragma unroll
  for (int r = 0; r < 4; ++r) linv[r] = 1.0f / __shfl(l, hi2 * 4 + r);
#pragma unroll
  for (int dt = 0; dt < 4; ++dt)
#pragma unroll
    for (int r = 0; r < 4; ++r) {
      int qrow = q0 + w * 16 + hi2 * 4 + r;
      Og[((size_t)(b * S_N) + qrow) * D_N + dt * 16 + q15] = o[dt][r] * linv[r];
    }
}

extern "C" void kernel_launch(void* const* d_in, const int* in_sizes, int n_in,
                              void* d_out, int out_size, void* d_ws, size_t ws_size,
                              hipStream_t stream) {
  const float* Qg = (const float*)d_in[0];
  const float* Kg = (const float*)d_in[1];
  const float* Vg = (const float*)d_in[2];
  const unsigned* mask = (const unsigned*)d_in[3];
  int* lens = (int*)d_ws;
  float* Og = (float*)d_out;

  lens_kernel<<<dim3(B_N), dim3(256), 0, stream>>>(mask, lens);
  attn_kernel<<<dim3(B_N * NQT), dim3(256), 0, stream>>>(Qg, Kg, Vg, lens, Og);
}

// Round 2
// 79.443 us; speedup vs baseline: 1.1768x; 1.1768x over previous
//
#include <hip/hip_runtime.h>
#include <hip/hip_bf16.h>

#define B_N 8
#define S_N 4096
#define D_N 64
#define BQ 64
#define BK 64
#define NQT (S_N / BQ)  // 64
#define TILE_BYTES 8192

typedef __attribute__((ext_vector_type(8))) short bf16x8;
typedef __attribute__((ext_vector_type(4))) float f32x4;

__device__ __forceinline__ float fast_exp2(float x) {
#if __has_builtin(__builtin_amdgcn_exp2f)
  return __builtin_amdgcn_exp2f(x);
#else
  return exp2f(x);
#endif
}

__device__ __forceinline__ unsigned f2bf_u(float x) {
  __hip_bfloat16 h = __float2bfloat16(x);
  return (unsigned)__builtin_bit_cast(unsigned short, h);
}
__device__ __forceinline__ unsigned pack2(float a, float b) {
  return f2bf_u(a) | (f2bf_u(b) << 16);
}
// XOR swizzle within a 128B-row tile (3-bit xor on the 16B-slot index)
__device__ __forceinline__ int swzoff(int row, int colb) {
  return row * 128 + (colb ^ ((((row & 7) ^ ((row >> 3) & 7))) << 4));
}

// LDS map (main kernel): K bf16 [2 buf][8KB] | V^T bf16 [2 buf][8KB] | P strip [4 w][2KB]
#define KB_OFF 0
#define VB_OFF 16384
#define PB_OFF 32768

// async global->LDS, 16B per lane, LDS dest = wave-uniform base + lane*16
#define GLOAD(g, l)                                                  \
  __builtin_amdgcn_global_load_lds(                                  \
      (const __attribute__((address_space(1))) unsigned*)(g),        \
      (__attribute__((address_space(3))) unsigned*)(l), 16, 0, 0)

__global__ void __launch_bounds__(256)
lens_kernel(const unsigned* __restrict__ mask, int* __restrict__ lens) {
  int b = blockIdx.x, tid = threadIdx.x;
  unsigned first = mask[0];  // mask[0][0] always valid (lens >= S/2)
  int cnt = 0;
  if (first == 0x01010101u) {          // bool / int8
    const unsigned char* m = ((const unsigned char*)mask) + (size_t)b * S_N;
    for (int i = tid; i < S_N; i += 256) cnt += (m[i] != 0);
  } else if (first == 0x3F800000u) {   // float
    const float* m = ((const float*)mask) + (size_t)b * S_N;
    for (int i = tid; i < S_N; i += 256) cnt += (m[i] != 0.0f);
  } else {                             // int32
    const int* m = ((const int*)mask) + (size_t)b * S_N;
    for (int i = tid; i < S_N; i += 256) cnt += (m[i] != 0);
  }
#pragma unroll
  for (int off = 32; off > 0; off >>= 1) cnt += __shfl_down(cnt, off);
  __shared__ int acc[4];
  if ((tid & 63) == 0) acc[tid >> 6] = cnt;
  __syncthreads();
  if (tid == 0) lens[b] = acc[0] + acc[1] + acc[2] + acc[3];
}

// One-time: K fp32 -> bf16 swizzled tiles; V fp32 -> V^T bf16 swizzled tiles.
// Tile (b,kt) is an 8KB image byte-identical to the main kernel's LDS layout.
__global__ void __launch_bounds__(256)
prep_kernel(const float* __restrict__ K, const float* __restrict__ V,
            char* __restrict__ Ks, char* __restrict__ VTs) {
  __shared__ float vl[64][72];  // V^T staging, rows 288B (16B aligned)
  const int bt = blockIdx.x, tid = threadIdx.x;
  const float* Kt = K + (size_t)bt * 4096;
  const float* Vt = V + (size_t)bt * 4096;
  char* Ko = Ks + (size_t)bt * TILE_BYTES;
  char* Vo = VTs + (size_t)bt * TILE_BYTES;
#pragma unroll
  for (int i = 0; i < 2; ++i) {
    int c = tid + i * 256;
    int r = c >> 3, j = c & 7;
    f32x4 a = *(const f32x4*)(Kt + r * 64 + j * 8);
    f32x4 b4 = *(const f32x4*)(Kt + r * 64 + j * 8 + 4);
    union { bf16x8 v; unsigned u[4]; } pk;
    pk.u[0] = pack2(a[0], a[1]);   pk.u[1] = pack2(a[2], a[3]);
    pk.u[2] = pack2(b4[0], b4[1]); pk.u[3] = pack2(b4[2], b4[3]);
    *(bf16x8*)(Ko + swzoff(r, j * 16)) = pk.v;
    f32x4 va = *(const f32x4*)(Vt + r * 64 + j * 8);
    f32x4 vb = *(const f32x4*)(Vt + r * 64 + j * 8 + 4);
#pragma unroll
    for (int e = 0; e < 4; ++e) vl[j * 8 + e][r] = va[e];
#pragma unroll
    for (int e = 0; e < 4; ++e) vl[j * 8 + 4 + e][r] = vb[e];
  }
  __syncthreads();
#pragma unroll
  for (int i = 0; i < 2; ++i) {
    int c = tid + i * 256;
    int d = c >> 3, j = c & 7;
    f32x4 fa = *(const f32x4*)(&vl[d][j * 8]);
    f32x4 fb = *(const f32x4*)(&vl[d][j * 8 + 4]);
    union { bf16x8 v; unsigned u[4]; } pk;
    pk.u[0] = pack2(fa[0], fa[1]); pk.u[1] = pack2(fa[2], fa[3]);
    pk.u[2] = pack2(fb[0], fb[1]); pk.u[3] = pack2(fb[2], fb[3]);
    *(bf16x8*)(Vo + swzoff(d, j * 16)) = pk.v;
  }
}

__global__ void __launch_bounds__(256)
attn_kernel(const float* __restrict__ Qg, const char* __restrict__ Ks,
            const char* __restrict__ VTs, const int* __restrict__ lens,
            float* __restrict__ Og) {
  __shared__ __align__(16) char sm[40960];
  const int tid = threadIdx.x;
  const int bid = blockIdx.x;
  const int b = bid & 7;                 // batch -> XCD pinning (K/V L2-resident)
  const int qt = (NQT - 1) - (bid >> 3); // heavy q-tiles first (LPT)
  const int q0 = qt * BQ;
  const int len = lens[b];
  int nt = (len + BK - 1) >> 6;
  if (qt + 1 < nt) nt = qt + 1;          // min(causal, padding)

  const int lane = tid & 63;
  const int w = tid >> 6;
  const int q15 = lane & 15;
  const int hi2 = lane >> 4;             // 0..3
  const int qg = q0 + w * 16 + q15;

  constexpr float CS = 0.125f * 1.4426950408889634f;  // scale * log2(e)

  // Q fragments (B-operand of swapped QK^T), scale folded in
  bf16x8 qf[2];
#pragma unroll
  for (int dc2 = 0; dc2 < 2; ++dc2) {
    const float* src = Qg + ((size_t)(b * S_N) + qg) * D_N + dc2 * 32 + hi2 * 8;
    f32x4 a = *(const f32x4*)src;
    f32x4 c4 = *(const f32x4*)(src + 4);
    union { bf16x8 v; unsigned u[4]; } pk;
    pk.u[0] = pack2(a[0] * CS, a[1] * CS);
    pk.u[1] = pack2(a[2] * CS, a[3] * CS);
    pk.u[2] = pack2(c4[0] * CS, c4[1] * CS);
    pk.u[3] = pack2(c4[2] * CS, c4[3] * CS);
    qf[dc2] = pk.v;
  }

  f32x4 o[4];
#pragma unroll
  for (int dt = 0; dt < 4; ++dt) o[dt] = (f32x4){0.f, 0.f, 0.f, 0.f};
  float m = -30000.0f, l = 0.0f;

  const char* Kb = Ks + (size_t)(b * NQT) * TILE_BYTES;
  const char* Vb = VTs + (size_t)(b * NQT) * TILE_BYTES;

  auto issue = [&](int t, int bf) {
    const char* ks = Kb + (size_t)t * TILE_BYTES + w * 2048 + lane * 16;
    const char* vs = Vb + (size_t)t * TILE_BYTES + w * 2048 + lane * 16;
    char* kd = sm + KB_OFF + bf * 8192 + w * 2048;
    char* vd = sm + VB_OFF + bf * 8192 + w * 2048;
    GLOAD(ks, kd);
    GLOAD(ks + 1024, kd + 1024);
    GLOAD(vs, vd);
    GLOAD(vs + 1024, vd + 1024);
  };

  issue(0, 0);

  for (int t = 0; t < nt; ++t) {
    const int buf = t & 1;
    const bool more = (t + 1) < nt;
    if (more) {
      issue(t + 1, buf ^ 1);                         // 4 new loads in flight
      asm volatile("s_waitcnt vmcnt(4)" ::: "memory");  // tile t landed
    } else {
      asm volatile("s_waitcnt vmcnt(0)" ::: "memory");
    }
    __builtin_amdgcn_sched_barrier(0);
    __builtin_amdgcn_s_barrier();
    __builtin_amdgcn_sched_barrier(0);

    // ---- S^T = K · Q^T : lane holds S[qg][k], k = ks16*16 + hi2*4 + r ----
    f32x4 st[4];
#pragma unroll
    for (int ks16 = 0; ks16 < 4; ++ks16) st[ks16] = (f32x4){0.f, 0.f, 0.f, 0.f};
#pragma unroll
    for (int dc2 = 0; dc2 < 2; ++dc2) {
#pragma unroll
      for (int ks16 = 0; ks16 < 4; ++ks16) {
        bf16x8 af = *(const bf16x8*)(sm + KB_OFF + buf * 8192 +
                                     swzoff(ks16 * 16 + q15, dc2 * 64 + hi2 * 16));
        st[ks16] = __builtin_amdgcn_mfma_f32_16x16x32_bf16(af, qf[dc2], st[ks16], 0, 0, 0);
      }
    }

    const int kv0 = t * BK;
    if (t == nt - 1) {  // only boundary tile needs causal+padding mask
#pragma unroll
      for (int ks16 = 0; ks16 < 4; ++ks16)
#pragma unroll
        for (int r = 0; r < 4; ++r) {
          int kg = kv0 + ks16 * 16 + hi2 * 4 + r;
          if (kg > qg || kg >= len) st[ks16][r] = -30000.0f;
        }
    }

    // ---- online softmax (base-2), defer-max (T13) ----
    float rmax = st[0][0];
#pragma unroll
    for (int ks16 = 0; ks16 < 4; ++ks16)
#pragma unroll
      for (int r = 0; r < 4; ++r) rmax = fmaxf(rmax, st[ks16][r]);
    rmax = fmaxf(rmax, __shfl_xor(rmax, 16));
    rmax = fmaxf(rmax, __shfl_xor(rmax, 32));
    if (!__all(rmax <= m + 8.0f)) {     // rescale only when max grew enough
      float mnew = fmaxf(m, rmax);
      float alpha = fast_exp2(m - mnew);
      m = mnew;
      l *= alpha;
      float ar[4];
#pragma unroll
      for (int r = 0; r < 4; ++r) ar[r] = __shfl(alpha, hi2 * 4 + r);
#pragma unroll
      for (int dt = 0; dt < 4; ++dt)
#pragma unroll
        for (int r = 0; r < 4; ++r) o[dt][r] *= ar[r];
    }
    float ps = 0.0f;
#pragma unroll
    for (int ks16 = 0; ks16 < 4; ++ks16)
#pragma unroll
      for (int r = 0; r < 4; ++r) {
        float p = fast_exp2(st[ks16][r] - m);  // bounded by 2^8 when deferred
        st[ks16][r] = p;
        ps += p;
      }
    ps += __shfl_xor(ps, 16);
    ps += __shfl_xor(ps, 32);
    l += ps;

    // ---- relay P through per-wave LDS strip (same-wave, no barrier) ----
#pragma unroll
    for (int ks16 = 0; ks16 < 4; ++ks16) {
      uint2 pw = make_uint2(pack2(st[ks16][0], st[ks16][1]),
                            pack2(st[ks16][2], st[ks16][3]));
      *(uint2*)(sm + PB_OFF + w * 2048 + swzoff(q15, ks16 * 32 + hi2 * 8)) = pw;
    }

    // ---- O += P · V ----
#pragma unroll
    for (int kc2 = 0; kc2 < 2; ++kc2) {
      bf16x8 pf = *(const bf16x8*)(sm + PB_OFF + w * 2048 +
                                   swzoff(q15, kc2 * 64 + hi2 * 16));
#pragma unroll
      for (int dt = 0; dt < 4; ++dt) {
        bf16x8 vfr = *(const bf16x8*)(sm + VB_OFF + buf * 8192 +
                                      swzoff(dt * 16 + q15, kc2 * 64 + hi2 * 16));
        o[dt] = __builtin_amdgcn_mfma_f32_16x16x32_bf16(pf, vfr, o[dt], 0, 0, 0);
      }
    }

    __builtin_amdgcn_sched_barrier(0);
    __builtin_amdgcn_s_barrier();   // buf free for reuse
    __builtin_amdgcn_sched_barrier(0);
  }

  // ---- epilogue: O /= l, store fp32 ----
  float linv[4];
#pragma unroll
  for (int r = 0; r < 4; ++r) linv[r] = 1.0f / __shfl(l, hi2 * 4 + r);
#pragma unroll
  for (int dt = 0; dt < 4; ++dt)
#pragma unroll
    for (int r = 0; r < 4; ++r) {
      int qrow = q0 + w * 16 + hi2 * 4 + r;
      Og[((size_t)(b * S_N) + qrow) * D_N + dt * 16 + q15] = o[dt][r] * linv[r];
    }
}

extern "C" void kernel_launch(void* const* d_in, const int* in_sizes, int n_in,
                              void* d_out, int out_size, void* d_ws, size_t ws_size,
                              hipStream_t stream) {
  const float* Qg = (const float*)d_in[0];
  const float* Kg = (const float*)d_in[1];
  const float* Vg = (const float*)d_in[2];
  const unsigned* mask = (const unsigned*)d_in[3];
  float* Og = (float*)d_out;

  int* lens = (int*)d_ws;
  char* Ks = (char*)d_ws + 4096;
  char* VTs = Ks + (size_t)B_N * NQT * TILE_BYTES;  // +4MB

  lens_kernel<<<dim3(B_N), dim3(256), 0, stream>>>(mask, lens);
  prep_kernel<<<dim3(B_N * NQT), dim3(256), 0, stream>>>(Kg, Vg, Ks, VTs);
  attn_kernel<<<dim3(B_N * NQT), dim3(256), 0, stream>>>(Qg, Ks, VTs, lens, Og);
}